// Round 2
// baseline (546.304 us; speedup 1.0000x reference)
//
#include <hip/hip_runtime.h>
#include <stdint.h>

typedef __bf16 bf16x8 __attribute__((ext_vector_type(8)));
typedef float f32x4 __attribute__((ext_vector_type(4)));

__device__ __forceinline__ float bf2f(uint16_t u) {
  union { uint32_t i; float f; } v; v.i = ((uint32_t)u) << 16; return v.f;
}
__device__ __forceinline__ uint16_t f2bf(float f) {
  union { float f; uint32_t i; } v; v.f = f;
  uint32_t u = v.i;
  uint32_t r = (u + 0x7FFFu + ((u >> 16) & 1u)) >> 16;
  return (uint16_t)r;
}
// gelu(v) = v * sigmoid(1.5957691*v*(1+0.044715*v^2))  (tanh-form identity).
__device__ __forceinline__ float fast_gelu(float v) {
  float t2 = v * v;
  float pz = 1.0f + 0.044715f * t2;
  float w = -1.5957691216f * v * pz;
  float e = __expf(w);
  return v * __builtin_amdgcn_rcpf(1.0f + e);
}
__device__ __forceinline__ void gld16(uint16_t* l, const uint16_t* g) {
  __builtin_amdgcn_global_load_lds(
      (const __attribute__((address_space(1))) void*)g,
      (__attribute__((address_space(3))) void*)l, 16, 0, 0);
}

// ---------------------------------------------------------------------------
// Kernel 0: convert fc1/fc2 weights fp32 -> bf16 into workspace.
// ---------------------------------------------------------------------------
__global__ __launch_bounds__(256) void cvt_weights_kernel(
    const float* __restrict__ fc1, const float* __restrict__ fc2,
    uint16_t* __restrict__ fc1b, uint16_t* __restrict__ fc2b)
{
  int i = (blockIdx.x * 256 + threadIdx.x) * 4;
  if (i < 262144) {
    float4 a = *(const float4*)(fc1 + i);
    ushort4 o;
    o.x = f2bf(a.x); o.y = f2bf(a.y); o.z = f2bf(a.z); o.w = f2bf(a.w);
    *(ushort4*)(fc1b + i) = o;
  } else {
    int j = i - 262144;
    float4 a = *(const float4*)(fc2 + j);
    ushort4 o;
    o.x = f2bf(a.x); o.y = f2bf(a.y); o.z = f2bf(a.z); o.w = f2bf(a.w);
    *(ushort4*)(fc2b + j) = o;
  }
}

// ---------------------------------------------------------------------------
// Kernel 1: NeoCell (block-diagonal A·X·B per channel) + BatchNorm(eval).
// x: NCHW fp32 (32,256,56,56) -> y1: (100352 x 256) row-major bf16 (NHWC).
// (unchanged from previous verified version)
// ---------------------------------------------------------------------------
__global__ __launch_bounds__(128) void neocell_bn_kernel(
    const float* __restrict__ x,
    const float* __restrict__ wa1, const float* __restrict__ wb1,
    const float* __restrict__ wa2, const float* __restrict__ wb2,
    const float* __restrict__ bnw, const float* __restrict__ bnb,
    const float* __restrict__ bnm, const float* __restrict__ bnv,
    uint16_t* __restrict__ y1)
{
  __shared__ uint16_t lx[128 * 226];
  const int t = threadIdx.x;        // 0..127
  const int strip = blockIdx.x;     // 0..13 (4-row strips)
  const int b = blockIdx.y;         // 0..31
  const int half = blockIdx.z;      // 0: k=2 channels, 1: k=4 channels
  const int h0 = strip * 4;

  for (int i = 0; i < 56; ++i) {
    int l = t + i * 128;
    int c = l / 56;
    int r = l - c * 56;
    const float* g = x + (size_t)(b * 256 + half * 128 + c) * 3136
                       + h0 * 56 + r * 4;
    float4 v = *(const float4*)g;
    ushort4 o;
    o.x = f2bf(v.x); o.y = f2bf(v.y); o.z = f2bf(v.z); o.w = f2bf(v.w);
    *(ushort4*)(lx + c * 226 + r * 4) = o;
  }
  __syncthreads();

  const int a = t & 63;
  const int p = t >> 6;
  const int c0 = half * 128 + 2 * a;

  float sc[2], sh[2];
#pragma unroll
  for (int ch = 0; ch < 2; ++ch) {
    int cg = c0 + ch;
    sc[ch] = bnw[cg] * rsqrtf(bnv[cg] + 1e-5f);
    sh[ch] = bnb[cg] - bnm[cg] * sc[ch];
  }
  const size_t pgbase = (size_t)b * 3136 + (size_t)h0 * 56;

  if (half == 0) {
    float A[2][2][2], Bm[2][2][2];
#pragma unroll
    for (int ch = 0; ch < 2; ++ch)
#pragma unroll
      for (int i = 0; i < 2; ++i)
#pragma unroll
        for (int j = 0; j < 2; ++j) {
          A[ch][i][j]  = wa1[(2 * a + ch) * 4 + i * 2 + j];
          Bm[ch][i][j] = wb1[(2 * a + ch) * 4 + i * 2 + j];
        }
    for (int m = 0; m < 28; ++m) {
      float O[2][2][2];
#pragma unroll
      for (int ch = 0; ch < 2; ++ch) {
        const uint16_t* lc = lx + (2 * a + ch) * 226 + (2 * p) * 56 + m * 2;
        uint32_t w0 = *(const uint32_t*)lc;
        uint32_t w1 = *(const uint32_t*)(lc + 56);
        float X[2][2];
        X[0][0] = bf2f((uint16_t)w0); X[0][1] = bf2f((uint16_t)(w0 >> 16));
        X[1][0] = bf2f((uint16_t)w1); X[1][1] = bf2f((uint16_t)(w1 >> 16));
        float T[2][2];
#pragma unroll
        for (int pp = 0; pp < 2; ++pp)
#pragma unroll
          for (int j = 0; j < 2; ++j)
            T[pp][j] = A[ch][pp][0] * X[0][j] + A[ch][pp][1] * X[1][j];
#pragma unroll
        for (int pp = 0; pp < 2; ++pp)
#pragma unroll
          for (int q = 0; q < 2; ++q)
            O[ch][pp][q] = (T[pp][0] * Bm[ch][0][q] + T[pp][1] * Bm[ch][1][q])
                           * sc[ch] + sh[ch];
      }
#pragma unroll
      for (int pp = 0; pp < 2; ++pp)
#pragma unroll
        for (int q = 0; q < 2; ++q) {
          uint32_t pk = (uint32_t)f2bf(O[0][pp][q])
                      | ((uint32_t)f2bf(O[1][pp][q]) << 16);
          size_t pg = pgbase + (size_t)(2 * p + pp) * 56 + (m * 2 + q);
          *(uint32_t*)(y1 + pg * 256 + c0) = pk;
        }
    }
  } else {
    float A[2][4][4], Bm[2][4][4];
#pragma unroll
    for (int ch = 0; ch < 2; ++ch)
#pragma unroll
      for (int i = 0; i < 4; ++i)
#pragma unroll
        for (int j = 0; j < 4; ++j) {
          A[ch][i][j]  = wa2[(2 * a + ch) * 16 + i * 4 + j];
          Bm[ch][i][j] = wb2[(2 * a + ch) * 16 + i * 4 + j];
        }
    for (int mm = 0; mm < 7; ++mm) {
      int m = 2 * mm + p;
      float O[2][4][4];
#pragma unroll
      for (int ch = 0; ch < 2; ++ch) {
        float X[4][4];
#pragma unroll
        for (int i = 0; i < 4; ++i) {
          const uint16_t* lc = lx + (2 * a + ch) * 226 + i * 56 + m * 4;
          uint32_t w0 = *(const uint32_t*)lc;
          uint32_t w1 = *(const uint32_t*)(lc + 2);
          X[i][0] = bf2f((uint16_t)w0); X[i][1] = bf2f((uint16_t)(w0 >> 16));
          X[i][2] = bf2f((uint16_t)w1); X[i][3] = bf2f((uint16_t)(w1 >> 16));
        }
        float T[4][4];
#pragma unroll
        for (int pp = 0; pp < 4; ++pp)
#pragma unroll
          for (int j = 0; j < 4; ++j)
            T[pp][j] = A[ch][pp][0] * X[0][j] + A[ch][pp][1] * X[1][j]
                     + A[ch][pp][2] * X[2][j] + A[ch][pp][3] * X[3][j];
#pragma unroll
        for (int pp = 0; pp < 4; ++pp)
#pragma unroll
          for (int q = 0; q < 4; ++q)
            O[ch][pp][q] = (T[pp][0] * Bm[ch][0][q] + T[pp][1] * Bm[ch][1][q]
                          + T[pp][2] * Bm[ch][2][q] + T[pp][3] * Bm[ch][3][q])
                           * sc[ch] + sh[ch];
      }
#pragma unroll
      for (int pp = 0; pp < 4; ++pp)
#pragma unroll
        for (int q = 0; q < 4; ++q) {
          uint32_t pk = (uint32_t)f2bf(O[0][pp][q])
                      | ((uint32_t)f2bf(O[1][pp][q]) << 16);
          size_t pg = pgbase + (size_t)pp * 56 + (m * 4 + q);
          *(uint32_t*)(y1 + pg * 256 + c0) = pk;
        }
    }
  }
}

// ---------------------------------------------------------------------------
// Kernel 2: FUSED MLP. out = gelu(y1 @ fc1^T) @ fc2^T + x, h never touches HBM.
// Block = 128 pixels x 256 out channels. 8 chunks of 128 fc1-outputs:
//   stage 1: C1^T[kk][p] = (W1chunk rows) x (y1 rows) MFMA (K=256, BK=32,
//            waves 2x2). Operand swap puts 4 consecutive kk per lane-reg ->
//            GELU + pack -> one ds_write_b64 per fragment into h_c[p][kk]
//            (XOR-swizzled: byte ^= (p&7)<<4, same involution on read).
//   stage 2: out[p][c] += h_c (LDS A-operand) x W2 col-slice (streamed via
//            global_load_lds), K=128, waves 1x4, acc 128 f32/lane.
// Weights (1 MB) are block-invariant -> L2-resident per XCD.
// Epilogue: LDS transpose (two 128-ch halves) -> NCHW fp32 + residual.
// ---------------------------------------------------------------------------
__global__ __launch_bounds__(256, 2) void fused_mlp_kernel(
    const uint16_t* __restrict__ y1, const uint16_t* __restrict__ fc1b,
    const uint16_t* __restrict__ fc2b, float* __restrict__ out,
    const float* __restrict__ Xres)
{
  __shared__ uint16_t lds[24576];     // 48 KB
  uint16_t* ldsA = lds;               // stage-1 W1 slice   [0, 4096)
  uint16_t* ldsB = lds + 4096;        // stage-1 y1 slice   [4096, 8192)
  uint16_t* ldsH = lds + 8192;        // h_c 128x128 bf16   [8192, 24576)
                                      // stage-2 W2 slice reuses [0, 8192)
                                      // epilogue reuses lds[0, 16640)

  const int tid = threadIdx.x;
  const int lane = tid & 63;
  const int wid = tid >> 6;
  const int wm = wid & 1;             // stage-1 kk-half
  const int wn = wid >> 1;            // stage-1 p-half
  const int fm = lane & 15;
  const int fq = lane >> 4;

  const size_t pix0 = (size_t)blockIdx.x * 128;

  const int q0 = tid, q1 = tid + 256;
  const int r0 = q0 >> 2, s0 = q0 & 3;
  const int r1 = q1 >> 2, s1 = q1 & 3;
  const uint16_t* ya = y1 + (pix0 + r0) * 256 + s0 * 8;
  const uint16_t* yb = y1 + (pix0 + r1) * 256 + s1 * 8;

  f32x4 oacc[8][4];
#pragma unroll
  for (int i = 0; i < 8; ++i)
#pragma unroll
    for (int j = 0; j < 4; ++j) { f32x4 z = {0.f, 0.f, 0.f, 0.f}; oacc[i][j] = z; }

  for (int kc = 0; kc < 8; ++kc) {
    // ---- stage 1: C1^T[kk=0..127][p=0..127] over K=256 -------------------
    const uint16_t* w1b = fc1b + (size_t)(kc * 128) * 256;
    f32x4 c1[4][4];
#pragma unroll
    for (int i = 0; i < 4; ++i)
#pragma unroll
      for (int j = 0; j < 4; ++j) { f32x4 z = {0.f, 0.f, 0.f, 0.f}; c1[i][j] = z; }

    for (int j0 = 0; j0 < 256; j0 += 32) {
      __syncthreads();
      gld16(ldsA + q0 * 8, w1b + r0 * 256 + s0 * 8 + j0);
      gld16(ldsA + q1 * 8, w1b + r1 * 256 + s1 * 8 + j0);
      gld16(ldsB + q0 * 8, ya + j0);
      gld16(ldsB + q1 * 8, yb + j0);
      __syncthreads();

      bf16x8 af[4], bfr[4];
#pragma unroll
      for (int mt = 0; mt < 4; ++mt)
        af[mt] = *(const bf16x8*)(const void*)
                 (ldsA + (wm * 64 + mt * 16 + fm) * 32 + fq * 8);
#pragma unroll
      for (int nt = 0; nt < 4; ++nt)
        bfr[nt] = *(const bf16x8*)(const void*)
                  (ldsB + (wn * 64 + nt * 16 + fm) * 32 + fq * 8);
#pragma unroll
      for (int mt = 0; mt < 4; ++mt)
#pragma unroll
        for (int nt = 0; nt < 4; ++nt)
          c1[mt][nt] = __builtin_amdgcn_mfma_f32_16x16x32_bf16(
              af[mt], bfr[nt], c1[mt][nt], 0, 0, 0);
    }

    // ---- GELU + pack 4 consecutive kk -> swizzled ds_write_b64 -----------
    // lane value (mt,nt,r): kk = wm*64+mt*16+fq*4+r,  p = wn*64+nt*16+fm
    {
      const int p_base = wn * 64 + fm;
      const int kkb_base = wm * 64 + fq * 4;
#pragma unroll
      for (int nt = 0; nt < 4; ++nt) {
        const int p = p_base + nt * 16;
        const int sw = (p & 7) << 4;
        char* rowp = (char*)ldsH + p * 256;
#pragma unroll
        for (int mt = 0; mt < 4; ++mt) {
          const int kkb = kkb_base + mt * 16;
          uint32_t lo = (uint32_t)f2bf(fast_gelu(c1[mt][nt][0]))
                      | ((uint32_t)f2bf(fast_gelu(c1[mt][nt][1])) << 16);
          uint32_t hi = (uint32_t)f2bf(fast_gelu(c1[mt][nt][2]))
                      | ((uint32_t)f2bf(fast_gelu(c1[mt][nt][3])) << 16);
          *(uint64_t*)(rowp + ((kkb * 2) ^ sw)) = ((uint64_t)hi << 32) | lo;
        }
      }
    }

    // ---- stage 2: out[p][c] += h_c[p][kk] * W2[c][kc*128+kk], K=128 ------
    const uint16_t* w2b = fc2b + kc * 128;
    for (int k2 = 0; k2 < 128; k2 += 32) {
      __syncthreads();                 // h_c visible (1st iter) + lds reuse
#pragma unroll
      for (int s = 0; s < 4; ++s) {
        int q = tid + s * 256;         // 0..1023
        int c = q >> 2, sg = q & 3;
        gld16(lds + q * 8, w2b + c * 1024 + k2 + sg * 8);
      }
      __syncthreads();

      bf16x8 ah[8], bw[4];
#pragma unroll
      for (int mt = 0; mt < 8; ++mt) {
        int p = mt * 16 + fm;
        ah[mt] = *(const bf16x8*)(const void*)
                 ((char*)ldsH + p * 256 + (((k2 + fq * 8) * 2) ^ ((p & 7) << 4)));
      }
#pragma unroll
      for (int nt = 0; nt < 4; ++nt)
        bw[nt] = *(const bf16x8*)(const void*)
                 (lds + (wid * 64 + nt * 16 + fm) * 32 + fq * 8);
#pragma unroll
      for (int mt = 0; mt < 8; ++mt)
#pragma unroll
        for (int nt = 0; nt < 4; ++nt)
          oacc[mt][nt] = __builtin_amdgcn_mfma_f32_16x16x32_bf16(
              ah[mt], bw[nt], oacc[mt][nt], 0, 0, 0);
    }
  }

  // ---- epilogue: two 128-channel halves, transpose via LDS, +residual ----
#pragma unroll
  for (int hh = 0; hh < 2; ++hh) {
    __syncthreads();
    if ((wid >> 1) == hh) {
#pragma unroll
      for (int mt = 0; mt < 8; ++mt) {
        int m = mt * 16 + fq * 4;                  // pixel within tile
#pragma unroll
        for (int nt = 0; nt < 4; ++nt) {
          int nl = (wid & 1) * 64 + nt * 16 + fm;  // channel within half
#pragma unroll
          for (int r = 0; r < 4; ++r)
            lds[nl * 130 + m + r] = f2bf(oacc[mt][nt][r]);
        }
      }
    }
    __syncthreads();
    const int pl0 = tid & 31;
    const int cw = tid >> 5;
#pragma unroll
    for (int it = 0; it < 16; ++it) {
      int ch = cw + it * 8;
      int cgl = hh * 128 + ch;
#pragma unroll
      for (int e = 0; e < 4; ++e) {
        int pl = pl0 + e * 32;
        uint32_t pg = (uint32_t)pix0 + (uint32_t)pl;
        uint32_t bimg = pg / 3136u;
        uint32_t rem = pg - bimg * 3136u;
        size_t addr = ((size_t)bimg * 256 + cgl) * 3136 + rem;
        out[addr] = bf2f(lds[ch * 130 + pl]) + Xres[addr];
      }
    }
  }
}

// ---------------------------------------------------------------------------
// Launch: cvt weights -> neocell -> fused MLP (h never leaves LDS).
// ws: fc1b 512KB | fc2b 512KB | y1 51.4MB   (h eliminated)
// ---------------------------------------------------------------------------
extern "C" void kernel_launch(void* const* d_in, const int* in_sizes, int n_in,
                              void* d_out, int out_size, void* d_ws,
                              size_t ws_size, hipStream_t stream)
{
  const float* x   = (const float*)d_in[0];
  const float* wa1 = (const float*)d_in[1];
  const float* wb1 = (const float*)d_in[2];
  const float* wa2 = (const float*)d_in[3];
  const float* wb2 = (const float*)d_in[4];
  const float* bnw = (const float*)d_in[5];
  const float* bnb = (const float*)d_in[6];
  const float* bnm = (const float*)d_in[7];
  const float* bnv = (const float*)d_in[8];
  const float* fc1 = (const float*)d_in[9];
  const float* fc2 = (const float*)d_in[10];
  float* out = (float*)d_out;

  uint16_t* fc1b = (uint16_t*)d_ws;                 // 512 KB
  uint16_t* fc2b = fc1b + 262144;                   // 512 KB
  uint16_t* y1 = fc2b + 262144;                     // 51.4 MB

  cvt_weights_kernel<<<512, 256, 0, stream>>>(fc1, fc2, fc1b, fc2b);
  neocell_bn_kernel<<<dim3(14, 32, 2), 128, 0, stream>>>(
      x, wa1, wb1, wa2, wb2, bnw, bnb, bnm, bnv, y1);
  fused_mlp_kernel<<<784, 256, 0, stream>>>(y1, fc1b, fc2b, out, x);
}

// Round 3
// 430.094 us; speedup vs baseline: 1.2702x; 1.2702x over previous
//
#include <hip/hip_runtime.h>
#include <stdint.h>

typedef __bf16 bf16x8 __attribute__((ext_vector_type(8)));
typedef float f32x4 __attribute__((ext_vector_type(4)));

__device__ __forceinline__ float bf2f(uint16_t u) {
  union { uint32_t i; float f; } v; v.i = ((uint32_t)u) << 16; return v.f;
}
__device__ __forceinline__ uint16_t f2bf(float f) {
  union { float f; uint32_t i; } v; v.f = f;
  uint32_t u = v.i;
  uint32_t r = (u + 0x7FFFu + ((u >> 16) & 1u)) >> 16;
  return (uint16_t)r;
}
// gelu(v) = v * sigmoid(1.5957691*v*(1+0.044715*v^2))  (tanh-form identity).
__device__ __forceinline__ float fast_gelu(float v) {
  float t2 = v * v;
  float pz = 1.0f + 0.044715f * t2;
  float w = -1.5957691216f * v * pz;
  float e = __expf(w);
  return v * __builtin_amdgcn_rcpf(1.0f + e);
}

// ---------------------------------------------------------------------------
// Kernel 0: convert fc1/fc2 weights fp32 -> bf16 into workspace.
// ---------------------------------------------------------------------------
__global__ __launch_bounds__(256) void cvt_weights_kernel(
    const float* __restrict__ fc1, const float* __restrict__ fc2,
    uint16_t* __restrict__ fc1b, uint16_t* __restrict__ fc2b)
{
  int i = (blockIdx.x * 256 + threadIdx.x) * 4;
  if (i < 262144) {
    float4 a = *(const float4*)(fc1 + i);
    ushort4 o;
    o.x = f2bf(a.x); o.y = f2bf(a.y); o.z = f2bf(a.z); o.w = f2bf(a.w);
    *(ushort4*)(fc1b + i) = o;
  } else {
    int j = i - 262144;
    float4 a = *(const float4*)(fc2 + j);
    ushort4 o;
    o.x = f2bf(a.x); o.y = f2bf(a.y); o.z = f2bf(a.z); o.w = f2bf(a.w);
    *(ushort4*)(fc2b + j) = o;
  }
}

// ---------------------------------------------------------------------------
// Kernel 1 (v2): NeoCell + BatchNorm(eval).  x: NCHW fp32 -> y1 NHWC bf16.
// Occupancy fix vs v1: 64-channel tiles (LDS 28.9 KB vs 57 KB) -> 5 blocks/CU
// x 2 waves = 10 waves/CU (v1 was 4). One channel per thread; u16 stores are
// lane-contiguous (128 B per wave-store, 64-ch group = two full 64 B lines).
// LDS stride 226 u16 -> lane bank-stride 113 dwords == 17 mod 32: conflict-free.
// grid (14 strips, 32 imgs, 4 ch-groups); groups 0,1 = k2 ch 0..127,
// groups 2,3 = k4 ch 128..255 (k branch block-uniform).
// ---------------------------------------------------------------------------
__global__ __launch_bounds__(128) void neocell_bn_kernel(
    const float* __restrict__ x,
    const float* __restrict__ wa1, const float* __restrict__ wb1,
    const float* __restrict__ wa2, const float* __restrict__ wb2,
    const float* __restrict__ bnw, const float* __restrict__ bnb,
    const float* __restrict__ bnm, const float* __restrict__ bnv,
    uint16_t* __restrict__ y1)
{
  __shared__ uint16_t lx[64 * 226];   // 28928 B
  const int t = threadIdx.x;          // 0..127
  const int strip = blockIdx.x;       // 0..13 (4-row strips)
  const int b = blockIdx.y;           // 0..31
  const int grp = blockIdx.z;         // 0..3 (64-channel group)
  const int h0 = strip * 4;

  // Stage 64 channels x (4 rows x 56 cols) fp32 -> bf16 into LDS.
  for (int i = 0; i < 28; ++i) {
    int l = t + i * 128;              // 0..3583
    int c = l / 56;                   // channel 0..63
    int r = l - c * 56;               // float4 index 0..55 within strip
    const float* g = x + (size_t)(b * 256 + grp * 64 + c) * 3136
                       + h0 * 56 + r * 4;
    float4 v = *(const float4*)g;
    ushort4 o;
    o.x = f2bf(v.x); o.y = f2bf(v.y); o.z = f2bf(v.z); o.w = f2bf(v.w);
    *(ushort4*)(lx + c * 226 + r * 4) = o;
  }
  __syncthreads();

  const int c = t & 63;               // channel within group
  const int p = t >> 6;               // 0,1: row-block (k2) / col parity (k4)
  const int cg = grp * 64 + c;        // global channel

  const float sc = bnw[cg] * rsqrtf(bnv[cg] + 1e-5f);
  const float sh = bnb[cg] - bnm[cg] * sc;
  const size_t pgbase = (size_t)b * 3136 + (size_t)h0 * 56;
  const uint16_t* lc0 = lx + c * 226;

  if (grp < 2) {
    // k=2. Thread: channel cg; strip rows {2p,2p+1}; all 28 col-blocks.
    float A[2][2], Bm[2][2];
#pragma unroll
    for (int i = 0; i < 2; ++i)
#pragma unroll
      for (int j = 0; j < 2; ++j) {
        A[i][j]  = wa1[cg * 4 + i * 2 + j];
        Bm[i][j] = wb1[cg * 4 + i * 2 + j];
      }
    for (int m = 0; m < 28; ++m) {
      const uint16_t* lc = lc0 + (2 * p) * 56 + m * 2;
      uint32_t w0 = *(const uint32_t*)lc;
      uint32_t w1 = *(const uint32_t*)(lc + 56);
      float X[2][2];
      X[0][0] = bf2f((uint16_t)w0); X[0][1] = bf2f((uint16_t)(w0 >> 16));
      X[1][0] = bf2f((uint16_t)w1); X[1][1] = bf2f((uint16_t)(w1 >> 16));
      float T[2][2];
#pragma unroll
      for (int pp = 0; pp < 2; ++pp)
#pragma unroll
        for (int j = 0; j < 2; ++j)
          T[pp][j] = A[pp][0] * X[0][j] + A[pp][1] * X[1][j];
#pragma unroll
      for (int pp = 0; pp < 2; ++pp)
#pragma unroll
        for (int q = 0; q < 2; ++q) {
          float O = (T[pp][0] * Bm[0][q] + T[pp][1] * Bm[1][q]) * sc + sh;
          size_t pg = pgbase + (size_t)(2 * p + pp) * 56 + (m * 2 + q);
          y1[pg * 256 + cg] = f2bf(O);
        }
    }
  } else {
    // k=4. Thread: channel cg; all 4 strip rows; col-blocks m = 2*mm+p.
    const int ck = cg - 128;          // index into wa2/wb2
    float A[4][4], Bm[4][4];
#pragma unroll
    for (int i = 0; i < 4; ++i)
#pragma unroll
      for (int j = 0; j < 4; ++j) {
        A[i][j]  = wa2[ck * 16 + i * 4 + j];
        Bm[i][j] = wb2[ck * 16 + i * 4 + j];
      }
    for (int mm = 0; mm < 7; ++mm) {
      int m = 2 * mm + p;
      float X[4][4];
#pragma unroll
      for (int i = 0; i < 4; ++i) {
        const uint16_t* lc = lc0 + i * 56 + m * 4;
        uint32_t w0 = *(const uint32_t*)lc;
        uint32_t w1 = *(const uint32_t*)(lc + 2);
        X[i][0] = bf2f((uint16_t)w0); X[i][1] = bf2f((uint16_t)(w0 >> 16));
        X[i][2] = bf2f((uint16_t)w1); X[i][3] = bf2f((uint16_t)(w1 >> 16));
      }
      float T[4][4];
#pragma unroll
      for (int pp = 0; pp < 4; ++pp)
#pragma unroll
        for (int j = 0; j < 4; ++j)
          T[pp][j] = A[pp][0] * X[0][j] + A[pp][1] * X[1][j]
                   + A[pp][2] * X[2][j] + A[pp][3] * X[3][j];
#pragma unroll
      for (int pp = 0; pp < 4; ++pp)
#pragma unroll
        for (int q = 0; q < 4; ++q) {
          float O = (T[pp][0] * Bm[0][q] + T[pp][1] * Bm[1][q]
                   + T[pp][2] * Bm[2][q] + T[pp][3] * Bm[3][q]) * sc + sh;
          size_t pg = pgbase + (size_t)pp * 56 + (m * 4 + q);
          y1[pg * 256 + cg] = f2bf(O);
        }
    }
  }
}

// ---------------------------------------------------------------------------
// m97-style GEMM (verified): C[row][col] = sum_k A[row][k] * B[col][k].
// 128x128 tile, BK=32, 4 waves 2x2, global_load_lds width=16.
// EPI 0: fast GELU -> h (rows x 1024 bf16).
// EPI 1: LDS-transpose epilogue -> NCHW fp32 out + fused fp32 residual.
// ---------------------------------------------------------------------------
template <int KD, int EPI>
__global__ __launch_bounds__(256) void gemm_bt_kernel(
    const uint16_t* __restrict__ A,     // rows x KD, row-major bf16
    const uint16_t* __restrict__ Bw,    // cols x KD, row-major bf16
    uint16_t* __restrict__ Cb16,        // EPI0 output (bf16)
    float* __restrict__ Cf32,           // EPI1 output (fp32 NCHW)
    const float* __restrict__ Xres,     // EPI1: residual (NCHW fp32)
    int chunk_pix0)                     // EPI1: global pixel offset of chunk
{
  __shared__ uint16_t lds[16640];       // K-loop: A[0..4096), B[4096..8192)
  uint16_t* ldsA = lds;                 // epilogue(EPI1): 128x130 bf16 tile
  uint16_t* ldsB = lds + 4096;

  const int tid = threadIdx.x;
  const int lane = tid & 63;
  const int wid = tid >> 6;
  const int wm = wid & 1;
  const int wn = wid >> 1;
  const int fm = lane & 15;             // MFMA row/col within 16
  const int fq = lane >> 4;             // quad

  const size_t arow0 = (size_t)blockIdx.y * 128;   // pixel-tile base
  const size_t brow0 = (size_t)blockIdx.x * 128;   // col-block base

  f32x4 acc[4][4];
#pragma unroll
  for (int i = 0; i < 4; ++i)
#pragma unroll
    for (int j = 0; j < 4; ++j) { f32x4 z = {0.f, 0.f, 0.f, 0.f}; acc[i][j] = z; }

  const int q0 = tid, q1 = tid + 256;
  const int r0 = q0 >> 2, kk0 = q0 & 3;
  const int r1 = q1 >> 2, kk1 = q1 & 3;
  const uint16_t* a0 = A + (arow0 + r0) * KD + kk0 * 8;
  const uint16_t* a1 = A + (arow0 + r1) * KD + kk1 * 8;
  const uint16_t* b0 = Bw + (brow0 + r0) * KD + kk0 * 8;
  const uint16_t* b1 = Bw + (brow0 + r1) * KD + kk1 * 8;

  for (int k0 = 0; k0 < KD; k0 += 32) {
    __syncthreads();
    __builtin_amdgcn_global_load_lds(
        (const __attribute__((address_space(1))) void*)(a0 + k0),
        (__attribute__((address_space(3))) void*)(ldsA + q0 * 8), 16, 0, 0);
    __builtin_amdgcn_global_load_lds(
        (const __attribute__((address_space(1))) void*)(a1 + k0),
        (__attribute__((address_space(3))) void*)(ldsA + q1 * 8), 16, 0, 0);
    __builtin_amdgcn_global_load_lds(
        (const __attribute__((address_space(1))) void*)(b0 + k0),
        (__attribute__((address_space(3))) void*)(ldsB + q0 * 8), 16, 0, 0);
    __builtin_amdgcn_global_load_lds(
        (const __attribute__((address_space(1))) void*)(b1 + k0),
        (__attribute__((address_space(3))) void*)(ldsB + q1 * 8), 16, 0, 0);
    __syncthreads();

    bf16x8 af[4], bfr[4];
#pragma unroll
    for (int mt = 0; mt < 4; ++mt)
      af[mt] = *(const bf16x8*)(const void*)
               (ldsA + (wm * 64 + mt * 16 + fm) * 32 + fq * 8);
#pragma unroll
    for (int nt = 0; nt < 4; ++nt)
      bfr[nt] = *(const bf16x8*)(const void*)
                (ldsB + (wn * 64 + nt * 16 + fm) * 32 + fq * 8);
#pragma unroll
    for (int mt = 0; mt < 4; ++mt)
#pragma unroll
      for (int nt = 0; nt < 4; ++nt)
        acc[mt][nt] = __builtin_amdgcn_mfma_f32_16x16x32_bf16(
            af[mt], bfr[nt], acc[mt][nt], 0, 0, 0);
  }

  if (EPI == 0) {
    // fast GELU -> h, row-major (rows x 1024) bf16.
    // D layout: col=lane&15, row=fq*4+r (m89/m91 verified).
#pragma unroll
    for (int mt = 0; mt < 4; ++mt) {
      const size_t rb = arow0 + wm * 64 + mt * 16 + fq * 4;
#pragma unroll
      for (int nt = 0; nt < 4; ++nt) {
        const size_t n = brow0 + wn * 64 + nt * 16 + fm;
#pragma unroll
        for (int r = 0; r < 4; ++r)
          Cb16[(rb + r) * 1024 + n] = f2bf(fast_gelu(acc[mt][nt][r]));
      }
    }
  } else {
    // Transpose through LDS -> pixel-contiguous NCHW fp32 stores + residual.
    __syncthreads();
#pragma unroll
    for (int mt = 0; mt < 4; ++mt) {
      int mbase = wm * 64 + mt * 16 + fq * 4;     // pixel within tile
#pragma unroll
      for (int nt = 0; nt < 4; ++nt) {
        int n = wn * 64 + nt * 16 + fm;           // channel within tile
#pragma unroll
        for (int r = 0; r < 4; ++r)
          lds[n * 130 + mbase + r] = f2bf(acc[mt][nt][r]);
      }
    }
    __syncthreads();
    const int pl0 = tid & 31;
    const int cw = tid >> 5;
#pragma unroll
    for (int it = 0; it < 16; ++it) {
      int ch = cw + it * 8;                        // channel within tile
      int cgl = (int)brow0 + ch;                   // global channel
#pragma unroll
      for (int e = 0; e < 4; ++e) {
        int pl = pl0 + e * 32;                     // pixel within tile
        uint32_t pg = (uint32_t)chunk_pix0 + blockIdx.y * 128u + (uint32_t)pl;
        uint32_t bimg = pg / 3136u;
        uint32_t rem = pg - bimg * 3136u;
        size_t addr = ((size_t)bimg * 256 + cgl) * 3136 + rem;
        Cf32[addr] = bf2f(lds[ch * 130 + pl]) + Xres[addr];
      }
    }
  }
}

// ---------------------------------------------------------------------------
// Launch: cvt weights -> neocell -> y1 (ws). Then chunked over pixel tiles:
//   GEMM1 (K=256)  y1 @ fc1^T -> gelu -> h (bf16, ws)
//   GEMM2 (K=1024) h @ fc2^T + x -> out (fp32 NCHW)
// ---------------------------------------------------------------------------
extern "C" void kernel_launch(void* const* d_in, const int* in_sizes, int n_in,
                              void* d_out, int out_size, void* d_ws,
                              size_t ws_size, hipStream_t stream)
{
  const float* x   = (const float*)d_in[0];
  const float* wa1 = (const float*)d_in[1];
  const float* wb1 = (const float*)d_in[2];
  const float* wa2 = (const float*)d_in[3];
  const float* wb2 = (const float*)d_in[4];
  const float* bnw = (const float*)d_in[5];
  const float* bnb = (const float*)d_in[6];
  const float* bnm = (const float*)d_in[7];
  const float* bnv = (const float*)d_in[8];
  const float* fc1 = (const float*)d_in[9];
  const float* fc2 = (const float*)d_in[10];
  float* out = (float*)d_out;

  uint16_t* fc1b = (uint16_t*)d_ws;                 // 512 KB
  uint16_t* fc2b = fc1b + 262144;                   // 512 KB
  uint16_t* y1 = fc2b + 262144;                     // 51.4 MB
  const size_t y1_elems = (size_t)100352 * 256;
  uint16_t* h = y1 + y1_elems;

  const long tiles_total = 784;                     // 100352 / 128
  const size_t fixed_bytes = (size_t)262144 * 4 + y1_elems * 2;
  long tiles_chunk = 1;
  if (ws_size > fixed_bytes + 262144) {
    tiles_chunk = (long)((ws_size - fixed_bytes) / (128ul * 1024ul * 2ul));
    if (tiles_chunk > tiles_total) tiles_chunk = tiles_total;
    if (tiles_chunk < 1) tiles_chunk = 1;
  }

  cvt_weights_kernel<<<512, 256, 0, stream>>>(fc1, fc2, fc1b, fc2b);
  neocell_bn_kernel<<<dim3(14, 32, 4), 128, 0, stream>>>(
      x, wa1, wb1, wa2, wb2, bnw, bnb, bnm, bnv, y1);

  for (long t0 = 0; t0 < tiles_total; t0 += tiles_chunk) {
    long T = tiles_total - t0;
    if (T > tiles_chunk) T = tiles_chunk;
    gemm_bt_kernel<256, 0><<<dim3(8, (uint32_t)T), 256, 0, stream>>>(
        y1 + (size_t)t0 * 128 * 256, fc1b, h, nullptr, nullptr, 0);
    gemm_bt_kernel<1024, 1><<<dim3(2, (uint32_t)T), 256, 0, stream>>>(
        h, fc2b, nullptr, out, x, (int)(t0 * 128));
  }
}

// Round 4
// 428.796 us; speedup vs baseline: 1.2740x; 1.0030x over previous
//
#include <hip/hip_runtime.h>
#include <stdint.h>

typedef __bf16 bf16x8 __attribute__((ext_vector_type(8)));
typedef float f32x4 __attribute__((ext_vector_type(4)));

__device__ __forceinline__ float bf2f(uint16_t u) {
  union { uint32_t i; float f; } v; v.i = ((uint32_t)u) << 16; return v.f;
}
__device__ __forceinline__ uint16_t f2bf(float f) {
  union { float f; uint32_t i; } v; v.f = f;
  uint32_t u = v.i;
  uint32_t r = (u + 0x7FFFu + ((u >> 16) & 1u)) >> 16;
  return (uint16_t)r;
}
// gelu(v) = v * sigmoid(1.5957691*v*(1+0.044715*v^2))  (tanh-form identity).
__device__ __forceinline__ float fast_gelu(float v) {
  float t2 = v * v;
  float pz = 1.0f + 0.044715f * t2;
  float w = -1.5957691216f * v * pz;
  float e = __expf(w);
  return v * __builtin_amdgcn_rcpf(1.0f + e);
}

// ---------------------------------------------------------------------------
// Kernel 0: convert fc1/fc2 weights fp32 -> bf16 into workspace.
// ---------------------------------------------------------------------------
__global__ __launch_bounds__(256) void cvt_weights_kernel(
    const float* __restrict__ fc1, const float* __restrict__ fc2,
    uint16_t* __restrict__ fc1b, uint16_t* __restrict__ fc2b)
{
  int i = (blockIdx.x * 256 + threadIdx.x) * 4;
  if (i < 262144) {
    float4 a = *(const float4*)(fc1 + i);
    ushort4 o;
    o.x = f2bf(a.x); o.y = f2bf(a.y); o.z = f2bf(a.z); o.w = f2bf(a.w);
    *(ushort4*)(fc1b + i) = o;
  } else {
    int j = i - 262144;
    float4 a = *(const float4*)(fc2 + j);
    ushort4 o;
    o.x = f2bf(a.x); o.y = f2bf(a.y); o.z = f2bf(a.z); o.w = f2bf(a.w);
    *(ushort4*)(fc2b + j) = o;
  }
}

// ---------------------------------------------------------------------------
// Kernel 1 (v2): NeoCell + BatchNorm(eval).  x: NCHW fp32 -> y1 NHWC bf16.
// (unchanged — verified; NOT occupancy-bound per r3 post-mortem, do not
// guess-tweak without a counter-backed theory)
// ---------------------------------------------------------------------------
__global__ __launch_bounds__(128) void neocell_bn_kernel(
    const float* __restrict__ x,
    const float* __restrict__ wa1, const float* __restrict__ wb1,
    const float* __restrict__ wa2, const float* __restrict__ wb2,
    const float* __restrict__ bnw, const float* __restrict__ bnb,
    const float* __restrict__ bnm, const float* __restrict__ bnv,
    uint16_t* __restrict__ y1)
{
  __shared__ uint16_t lx[64 * 226];   // 28928 B
  const int t = threadIdx.x;          // 0..127
  const int strip = blockIdx.x;       // 0..13 (4-row strips)
  const int b = blockIdx.y;           // 0..31
  const int grp = blockIdx.z;         // 0..3 (64-channel group)
  const int h0 = strip * 4;

  for (int i = 0; i < 28; ++i) {
    int l = t + i * 128;              // 0..3583
    int c = l / 56;                   // channel 0..63
    int r = l - c * 56;               // float4 index 0..55 within strip
    const float* g = x + (size_t)(b * 256 + grp * 64 + c) * 3136
                       + h0 * 56 + r * 4;
    float4 v = *(const float4*)g;
    ushort4 o;
    o.x = f2bf(v.x); o.y = f2bf(v.y); o.z = f2bf(v.z); o.w = f2bf(v.w);
    *(ushort4*)(lx + c * 226 + r * 4) = o;
  }
  __syncthreads();

  const int c = t & 63;               // channel within group
  const int p = t >> 6;               // 0,1: row-block (k2) / col parity (k4)
  const int cg = grp * 64 + c;        // global channel

  const float sc = bnw[cg] * rsqrtf(bnv[cg] + 1e-5f);
  const float sh = bnb[cg] - bnm[cg] * sc;
  const size_t pgbase = (size_t)b * 3136 + (size_t)h0 * 56;
  const uint16_t* lc0 = lx + c * 226;

  if (grp < 2) {
    float A[2][2], Bm[2][2];
#pragma unroll
    for (int i = 0; i < 2; ++i)
#pragma unroll
      for (int j = 0; j < 2; ++j) {
        A[i][j]  = wa1[cg * 4 + i * 2 + j];
        Bm[i][j] = wb1[cg * 4 + i * 2 + j];
      }
    for (int m = 0; m < 28; ++m) {
      const uint16_t* lc = lc0 + (2 * p) * 56 + m * 2;
      uint32_t w0 = *(const uint32_t*)lc;
      uint32_t w1 = *(const uint32_t*)(lc + 56);
      float X[2][2];
      X[0][0] = bf2f((uint16_t)w0); X[0][1] = bf2f((uint16_t)(w0 >> 16));
      X[1][0] = bf2f((uint16_t)w1); X[1][1] = bf2f((uint16_t)(w1 >> 16));
      float T[2][2];
#pragma unroll
      for (int pp = 0; pp < 2; ++pp)
#pragma unroll
        for (int j = 0; j < 2; ++j)
          T[pp][j] = A[pp][0] * X[0][j] + A[pp][1] * X[1][j];
#pragma unroll
      for (int pp = 0; pp < 2; ++pp)
#pragma unroll
        for (int q = 0; q < 2; ++q) {
          float O = (T[pp][0] * Bm[0][q] + T[pp][1] * Bm[1][q]) * sc + sh;
          size_t pg = pgbase + (size_t)(2 * p + pp) * 56 + (m * 2 + q);
          y1[pg * 256 + cg] = f2bf(O);
        }
    }
  } else {
    const int ck = cg - 128;          // index into wa2/wb2
    float A[4][4], Bm[4][4];
#pragma unroll
    for (int i = 0; i < 4; ++i)
#pragma unroll
      for (int j = 0; j < 4; ++j) {
        A[i][j]  = wa2[ck * 16 + i * 4 + j];
        Bm[i][j] = wb2[ck * 16 + i * 4 + j];
      }
    for (int mm = 0; mm < 7; ++mm) {
      int m = 2 * mm + p;
      float X[4][4];
#pragma unroll
      for (int i = 0; i < 4; ++i) {
        const uint16_t* lc = lc0 + i * 56 + m * 4;
        uint32_t w0 = *(const uint32_t*)lc;
        uint32_t w1 = *(const uint32_t*)(lc + 2);
        X[i][0] = bf2f((uint16_t)w0); X[i][1] = bf2f((uint16_t)(w0 >> 16));
        X[i][2] = bf2f((uint16_t)w1); X[i][3] = bf2f((uint16_t)(w1 >> 16));
      }
      float T[4][4];
#pragma unroll
      for (int pp = 0; pp < 4; ++pp)
#pragma unroll
        for (int j = 0; j < 4; ++j)
          T[pp][j] = A[pp][0] * X[0][j] + A[pp][1] * X[1][j]
                   + A[pp][2] * X[2][j] + A[pp][3] * X[3][j];
#pragma unroll
      for (int pp = 0; pp < 4; ++pp)
#pragma unroll
        for (int q = 0; q < 4; ++q) {
          float O = (T[pp][0] * Bm[0][q] + T[pp][1] * Bm[1][q]
                   + T[pp][2] * Bm[2][q] + T[pp][3] * Bm[3][q]) * sc + sh;
          size_t pg = pgbase + (size_t)pp * 56 + (m * 4 + q);
          y1[pg * 256 + cg] = f2bf(O);
        }
    }
  }
}

// ---------------------------------------------------------------------------
// m97-style GEMM (verified): C[row][col] = sum_k A[row][k] * B[col][k].
// 128x128 tile, BK=32, 4 waves 2x2, global_load_lds width=16.
// NEW: XCD-chunk swizzle — HW round-robins linear block id across 8 XCDs;
// remap w=(lid&7)*(n/8)+(lid>>3) so each XCD owns a CONTIGUOUS run of
// pixel-tiles (A-tiles + weights L2-local). Bijective iff n%8==0 (guarded).
// EPI 0: fast GELU -> h (rows x 1024 bf16).
// EPI 1: LDS-transpose epilogue -> NCHW fp32 out + fused fp32 residual.
// ---------------------------------------------------------------------------
template <int KD, int EPI>
__global__ __launch_bounds__(256) void gemm_bt_kernel(
    const uint16_t* __restrict__ A,     // rows x KD, row-major bf16
    const uint16_t* __restrict__ Bw,    // cols x KD, row-major bf16
    uint16_t* __restrict__ Cb16,        // EPI0 output (bf16)
    float* __restrict__ Cf32,           // EPI1 output (fp32 NCHW)
    const float* __restrict__ Xres,     // EPI1: residual (NCHW fp32)
    int chunk_pix0)                     // EPI1: global pixel offset of chunk
{
  __shared__ uint16_t lds[16640];       // K-loop: A[0..4096), B[4096..8192)
  uint16_t* ldsA = lds;                 // epilogue(EPI1): 128x130 bf16 tile
  uint16_t* ldsB = lds + 4096;

  const int tid = threadIdx.x;
  const int lane = tid & 63;
  const int wid = tid >> 6;
  const int wm = wid & 1;
  const int wn = wid >> 1;
  const int fm = lane & 15;             // MFMA row/col within 16
  const int fq = lane >> 4;             // quad

  // XCD-chunk swizzle (T1). lid = hw linear id (x fastest).
  uint32_t nx = gridDim.x;
  uint32_t n = nx * gridDim.y;
  uint32_t lid = blockIdx.y * nx + blockIdx.x;
  uint32_t bx, by;
  if ((n & 7u) == 0u) {
    uint32_t w = (lid & 7u) * (n >> 3) + (lid >> 3);
    bx = w & (nx - 1u);                 // nx is 2 or 8 (pow2)
    by = w / nx;
  } else {
    bx = blockIdx.x; by = blockIdx.y;
  }

  const size_t arow0 = (size_t)by * 128;   // pixel-tile base
  const size_t brow0 = (size_t)bx * 128;   // col-block base

  f32x4 acc[4][4];
#pragma unroll
  for (int i = 0; i < 4; ++i)
#pragma unroll
    for (int j = 0; j < 4; ++j) { f32x4 z = {0.f, 0.f, 0.f, 0.f}; acc[i][j] = z; }

  const int q0 = tid, q1 = tid + 256;
  const int r0 = q0 >> 2, kk0 = q0 & 3;
  const int r1 = q1 >> 2, kk1 = q1 & 3;
  const uint16_t* a0 = A + (arow0 + r0) * KD + kk0 * 8;
  const uint16_t* a1 = A + (arow0 + r1) * KD + kk1 * 8;
  const uint16_t* b0 = Bw + (brow0 + r0) * KD + kk0 * 8;
  const uint16_t* b1 = Bw + (brow0 + r1) * KD + kk1 * 8;

  for (int k0 = 0; k0 < KD; k0 += 32) {
    __syncthreads();
    __builtin_amdgcn_global_load_lds(
        (const __attribute__((address_space(1))) void*)(a0 + k0),
        (__attribute__((address_space(3))) void*)(ldsA + q0 * 8), 16, 0, 0);
    __builtin_amdgcn_global_load_lds(
        (const __attribute__((address_space(1))) void*)(a1 + k0),
        (__attribute__((address_space(3))) void*)(ldsA + q1 * 8), 16, 0, 0);
    __builtin_amdgcn_global_load_lds(
        (const __attribute__((address_space(1))) void*)(b0 + k0),
        (__attribute__((address_space(3))) void*)(ldsB + q0 * 8), 16, 0, 0);
    __builtin_amdgcn_global_load_lds(
        (const __attribute__((address_space(1))) void*)(b1 + k0),
        (__attribute__((address_space(3))) void*)(ldsB + q1 * 8), 16, 0, 0);
    __syncthreads();

    bf16x8 af[4], bfr[4];
#pragma unroll
    for (int mt = 0; mt < 4; ++mt)
      af[mt] = *(const bf16x8*)(const void*)
               (ldsA + (wm * 64 + mt * 16 + fm) * 32 + fq * 8);
#pragma unroll
    for (int nt = 0; nt < 4; ++nt)
      bfr[nt] = *(const bf16x8*)(const void*)
                (ldsB + (wn * 64 + nt * 16 + fm) * 32 + fq * 8);
#pragma unroll
    for (int mt = 0; mt < 4; ++mt)
#pragma unroll
      for (int nt = 0; nt < 4; ++nt)
        acc[mt][nt] = __builtin_amdgcn_mfma_f32_16x16x32_bf16(
            af[mt], bfr[nt], acc[mt][nt], 0, 0, 0);
  }

  if (EPI == 0) {
    // fast GELU -> h, row-major (rows x 1024) bf16.
    // D layout: col=lane&15, row=fq*4+r (m89/m91 verified).
#pragma unroll
    for (int mt = 0; mt < 4; ++mt) {
      const size_t rb = arow0 + wm * 64 + mt * 16 + fq * 4;
#pragma unroll
      for (int nt = 0; nt < 4; ++nt) {
        const size_t n2 = brow0 + wn * 64 + nt * 16 + fm;
#pragma unroll
        for (int r = 0; r < 4; ++r)
          Cb16[(rb + r) * 1024 + n2] = f2bf(fast_gelu(acc[mt][nt][r]));
      }
    }
  } else {
    // Transpose through LDS -> pixel-contiguous NCHW fp32 stores + residual.
    __syncthreads();
#pragma unroll
    for (int mt = 0; mt < 4; ++mt) {
      int mbase = wm * 64 + mt * 16 + fq * 4;     // pixel within tile
#pragma unroll
      for (int nt = 0; nt < 4; ++nt) {
        int nn = wn * 64 + nt * 16 + fm;          // channel within tile
#pragma unroll
        for (int r = 0; r < 4; ++r)
          lds[nn * 130 + mbase + r] = f2bf(acc[mt][nt][r]);
      }
    }
    __syncthreads();
    const int pl0 = tid & 31;
    const int cw = tid >> 5;
#pragma unroll
    for (int it = 0; it < 16; ++it) {
      int ch = cw + it * 8;                        // channel within tile
      int cgl = (int)brow0 + ch;                   // global channel
#pragma unroll
      for (int e = 0; e < 4; ++e) {
        int pl = pl0 + e * 32;                     // pixel within tile
        uint32_t pg = (uint32_t)chunk_pix0 + by * 128u + (uint32_t)pl;
        uint32_t bimg = pg / 3136u;
        uint32_t rem = pg - bimg * 3136u;
        size_t addr = ((size_t)bimg * 256 + cgl) * 3136 + rem;
        Cf32[addr] = bf2f(lds[ch * 130 + pl]) + Xres[addr];
      }
    }
  }
}

// ---------------------------------------------------------------------------
// Launch: cvt weights -> neocell -> y1 (ws). Then chunked over pixel tiles:
//   GEMM1 (K=256)  y1 @ fc1^T -> gelu -> h (bf16, ws)
//   GEMM2 (K=1024) h @ fc2^T + x -> out (fp32 NCHW)
// tiles_chunk capped at 392 so each h-chunk (103 MB) stays L3-resident
// between producer and consumer — kills most of the 410 MB h HBM roundtrip.
// ---------------------------------------------------------------------------
extern "C" void kernel_launch(void* const* d_in, const int* in_sizes, int n_in,
                              void* d_out, int out_size, void* d_ws,
                              size_t ws_size, hipStream_t stream)
{
  const float* x   = (const float*)d_in[0];
  const float* wa1 = (const float*)d_in[1];
  const float* wb1 = (const float*)d_in[2];
  const float* wa2 = (const float*)d_in[3];
  const float* wb2 = (const float*)d_in[4];
  const float* bnw = (const float*)d_in[5];
  const float* bnb = (const float*)d_in[6];
  const float* bnm = (const float*)d_in[7];
  const float* bnv = (const float*)d_in[8];
  const float* fc1 = (const float*)d_in[9];
  const float* fc2 = (const float*)d_in[10];
  float* out = (float*)d_out;

  uint16_t* fc1b = (uint16_t*)d_ws;                 // 512 KB
  uint16_t* fc2b = fc1b + 262144;                   // 512 KB
  uint16_t* y1 = fc2b + 262144;                     // 51.4 MB
  const size_t y1_elems = (size_t)100352 * 256;
  uint16_t* h = y1 + y1_elems;

  const long tiles_total = 784;                     // 100352 / 128
  const size_t fixed_bytes = (size_t)262144 * 4 + y1_elems * 2;
  long tiles_chunk = 1;
  if (ws_size > fixed_bytes + 262144) {
    tiles_chunk = (long)((ws_size - fixed_bytes) / (128ul * 1024ul * 2ul));
    if (tiles_chunk > 392) tiles_chunk = 392;       // L3-resident h chunks
    if (tiles_chunk < 1) tiles_chunk = 1;
  }

  cvt_weights_kernel<<<512, 256, 0, stream>>>(fc1, fc2, fc1b, fc2b);
  neocell_bn_kernel<<<dim3(14, 32, 4), 128, 0, stream>>>(
      x, wa1, wb1, wa2, wb2, bnw, bnb, bnm, bnv, y1);

  for (long t0 = 0; t0 < tiles_total; t0 += tiles_chunk) {
    long T = tiles_total - t0;
    if (T > tiles_chunk) T = tiles_chunk;
    gemm_bt_kernel<256, 0><<<dim3(8, (uint32_t)T), 256, 0, stream>>>(
        y1 + (size_t)t0 * 128 * 256, fc1b, h, nullptr, nullptr, 0);
    gemm_bt_kernel<1024, 1><<<dim3(2, (uint32_t)T), 256, 0, stream>>>(
        h, fc2b, nullptr, out, x, (int)(t0 * 128));
  }
}

// Round 5
// 412.252 us; speedup vs baseline: 1.3252x; 1.0401x over previous
//
#include <hip/hip_runtime.h>
#include <stdint.h>

typedef __bf16 bf16x8 __attribute__((ext_vector_type(8)));
typedef float f32x4 __attribute__((ext_vector_type(4)));

__device__ __forceinline__ float bf2f(uint16_t u) {
  union { uint32_t i; float f; } v; v.i = ((uint32_t)u) << 16; return v.f;
}
__device__ __forceinline__ uint16_t f2bf(float f) {
  union { float f; uint32_t i; } v; v.f = f;
  uint32_t u = v.i;
  uint32_t r = (u + 0x7FFFu + ((u >> 16) & 1u)) >> 16;
  return (uint16_t)r;
}
// gelu(v) = v * sigmoid(1.5957691*v*(1+0.044715*v^2))  (tanh-form identity).
__device__ __forceinline__ float fast_gelu(float v) {
  float t2 = v * v;
  float pz = 1.0f + 0.044715f * t2;
  float w = -1.5957691216f * v * pz;
  float e = __expf(w);
  return v * __builtin_amdgcn_rcpf(1.0f + e);
}
__device__ __forceinline__ void gld16(uint16_t* l, const uint16_t* g) {
  __builtin_amdgcn_global_load_lds(
      (const __attribute__((address_space(1))) void*)g,
      (__attribute__((address_space(3))) void*)l, 16, 0, 0);
}

// ---------------------------------------------------------------------------
// Kernel 0: convert fc1/fc2 weights fp32 -> bf16 into workspace.
// ---------------------------------------------------------------------------
__global__ __launch_bounds__(256) void cvt_weights_kernel(
    const float* __restrict__ fc1, const float* __restrict__ fc2,
    uint16_t* __restrict__ fc1b, uint16_t* __restrict__ fc2b)
{
  int i = (blockIdx.x * 256 + threadIdx.x) * 4;
  if (i < 262144) {
    float4 a = *(const float4*)(fc1 + i);
    ushort4 o;
    o.x = f2bf(a.x); o.y = f2bf(a.y); o.z = f2bf(a.z); o.w = f2bf(a.w);
    *(ushort4*)(fc1b + i) = o;
  } else {
    int j = i - 262144;
    float4 a = *(const float4*)(fc2 + j);
    ushort4 o;
    o.x = f2bf(a.x); o.y = f2bf(a.y); o.z = f2bf(a.z); o.w = f2bf(a.w);
    *(ushort4*)(fc2b + j) = o;
  }
}

// ---------------------------------------------------------------------------
// Kernel 1 (v2): NeoCell + BatchNorm(eval).  x: NCHW fp32 -> y1 NHWC bf16.
// (unchanged — verified; r4 top-5 cutoff proves it runs < 72 us)
// ---------------------------------------------------------------------------
__global__ __launch_bounds__(128) void neocell_bn_kernel(
    const float* __restrict__ x,
    const float* __restrict__ wa1, const float* __restrict__ wb1,
    const float* __restrict__ wa2, const float* __restrict__ wb2,
    const float* __restrict__ bnw, const float* __restrict__ bnb,
    const float* __restrict__ bnm, const float* __restrict__ bnv,
    uint16_t* __restrict__ y1)
{
  __shared__ uint16_t lx[64 * 226];   // 28928 B
  const int t = threadIdx.x;          // 0..127
  const int strip = blockIdx.x;       // 0..13 (4-row strips)
  const int b = blockIdx.y;           // 0..31
  const int grp = blockIdx.z;         // 0..3 (64-channel group)
  const int h0 = strip * 4;

  for (int i = 0; i < 28; ++i) {
    int l = t + i * 128;              // 0..3583
    int c = l / 56;                   // channel 0..63
    int r = l - c * 56;               // float4 index 0..55 within strip
    const float* g = x + (size_t)(b * 256 + grp * 64 + c) * 3136
                       + h0 * 56 + r * 4;
    float4 v = *(const float4*)g;
    ushort4 o;
    o.x = f2bf(v.x); o.y = f2bf(v.y); o.z = f2bf(v.z); o.w = f2bf(v.w);
    *(ushort4*)(lx + c * 226 + r * 4) = o;
  }
  __syncthreads();

  const int c = t & 63;               // channel within group
  const int p = t >> 6;               // 0,1: row-block (k2) / col parity (k4)
  const int cg = grp * 64 + c;        // global channel

  const float sc = bnw[cg] * rsqrtf(bnv[cg] + 1e-5f);
  const float sh = bnb[cg] - bnm[cg] * sc;
  const size_t pgbase = (size_t)b * 3136 + (size_t)h0 * 56;
  const uint16_t* lc0 = lx + c * 226;

  if (grp < 2) {
    float A[2][2], Bm[2][2];
#pragma unroll
    for (int i = 0; i < 2; ++i)
#pragma unroll
      for (int j = 0; j < 2; ++j) {
        A[i][j]  = wa1[cg * 4 + i * 2 + j];
        Bm[i][j] = wb1[cg * 4 + i * 2 + j];
      }
    for (int m = 0; m < 28; ++m) {
      const uint16_t* lc = lc0 + (2 * p) * 56 + m * 2;
      uint32_t w0 = *(const uint32_t*)lc;
      uint32_t w1 = *(const uint32_t*)(lc + 56);
      float X[2][2];
      X[0][0] = bf2f((uint16_t)w0); X[0][1] = bf2f((uint16_t)(w0 >> 16));
      X[1][0] = bf2f((uint16_t)w1); X[1][1] = bf2f((uint16_t)(w1 >> 16));
      float T[2][2];
#pragma unroll
      for (int pp = 0; pp < 2; ++pp)
#pragma unroll
        for (int j = 0; j < 2; ++j)
          T[pp][j] = A[pp][0] * X[0][j] + A[pp][1] * X[1][j];
#pragma unroll
      for (int pp = 0; pp < 2; ++pp)
#pragma unroll
        for (int q = 0; q < 2; ++q) {
          float O = (T[pp][0] * Bm[0][q] + T[pp][1] * Bm[1][q]) * sc + sh;
          size_t pg = pgbase + (size_t)(2 * p + pp) * 56 + (m * 2 + q);
          y1[pg * 256 + cg] = f2bf(O);
        }
    }
  } else {
    const int ck = cg - 128;          // index into wa2/wb2
    float A[4][4], Bm[4][4];
#pragma unroll
    for (int i = 0; i < 4; ++i)
#pragma unroll
      for (int j = 0; j < 4; ++j) {
        A[i][j]  = wa2[ck * 16 + i * 4 + j];
        Bm[i][j] = wb2[ck * 16 + i * 4 + j];
      }
    for (int mm = 0; mm < 7; ++mm) {
      int m = 2 * mm + p;
      float X[4][4];
#pragma unroll
      for (int i = 0; i < 4; ++i) {
        const uint16_t* lc = lc0 + i * 56 + m * 4;
        uint32_t w0 = *(const uint32_t*)lc;
        uint32_t w1 = *(const uint32_t*)(lc + 2);
        X[i][0] = bf2f((uint16_t)w0); X[i][1] = bf2f((uint16_t)(w0 >> 16));
        X[i][2] = bf2f((uint16_t)w1); X[i][3] = bf2f((uint16_t)(w1 >> 16));
      }
      float T[4][4];
#pragma unroll
      for (int pp = 0; pp < 4; ++pp)
#pragma unroll
        for (int j = 0; j < 4; ++j)
          T[pp][j] = A[pp][0] * X[0][j] + A[pp][1] * X[1][j]
                   + A[pp][2] * X[2][j] + A[pp][3] * X[3][j];
#pragma unroll
      for (int pp = 0; pp < 4; ++pp)
#pragma unroll
        for (int q = 0; q < 4; ++q) {
          float O = (T[pp][0] * Bm[0][q] + T[pp][1] * Bm[1][q]
                   + T[pp][2] * Bm[2][q] + T[pp][3] * Bm[3][q]) * sc + sh;
          size_t pg = pgbase + (size_t)pp * 56 + (m * 4 + q);
          y1[pg * 256 + cg] = f2bf(O);
        }
    }
  }
}

// ---------------------------------------------------------------------------
// GEMM (pipelined v2): C[row][col] = sum_k A[row][k] * B[col][k].
// 128x128 tile, BK=32, 4 waves 2x2, global_load_lds width=16.
// T3 minimum-2-phase: double-buffered LDS; per 32-K phase
//   {STAGE next tile -> other buf; ds_read cur buf; MFMA; __syncthreads()}.
// Loads for tile t+1 issue BEFORE tile t's compute, drain AFTER it (the
// barrier's vmcnt(0)) -> load latency hides under MFMA+ds_read; 1 barrier
// per K-step instead of 2. LDS total unchanged (33280 B: 4x4096-u16 bufs;
// epilogue 128x130 tile reuses the same allocation after the final barrier).
// XCD-chunk swizzle kept (bijective, n%8==0 for both grids).
// EPI 0: fast GELU -> h (rows x 1024 bf16).
// EPI 1: LDS-transpose epilogue -> NCHW fp32 out + fused fp32 residual.
// ---------------------------------------------------------------------------
template <int KD, int EPI>
__global__ __launch_bounds__(256) void gemm_bt_kernel(
    const uint16_t* __restrict__ A,     // rows x KD, row-major bf16
    const uint16_t* __restrict__ Bw,    // cols x KD, row-major bf16
    uint16_t* __restrict__ Cb16,        // EPI0 output (bf16)
    float* __restrict__ Cf32,           // EPI1 output (fp32 NCHW)
    const float* __restrict__ Xres,     // EPI1: residual (NCHW fp32)
    int chunk_pix0)                     // EPI1: global pixel offset of chunk
{
  __shared__ uint16_t lds[16640];       // dbuf A0|B0|A1|B1 (4x4096 u16)
  uint16_t* A0 = lds;                   // epilogue: 128x130 bf16 tile reuse
  uint16_t* B0 = lds + 4096;
  uint16_t* A1 = lds + 8192;
  uint16_t* B1 = lds + 12288;

  const int tid = threadIdx.x;
  const int lane = tid & 63;
  const int wid = tid >> 6;
  const int wm = wid & 1;
  const int wn = wid >> 1;
  const int fm = lane & 15;             // MFMA row/col within 16
  const int fq = lane >> 4;             // quad

  // XCD-chunk swizzle (T1). lid = hw linear id (x fastest).
  uint32_t nx = gridDim.x;
  uint32_t n = nx * gridDim.y;
  uint32_t lid = blockIdx.y * nx + blockIdx.x;
  uint32_t bx, by;
  if ((n & 7u) == 0u) {
    uint32_t w = (lid & 7u) * (n >> 3) + (lid >> 3);
    bx = w & (nx - 1u);                 // nx is 2 or 8 (pow2)
    by = w / nx;
  } else {
    bx = blockIdx.x; by = blockIdx.y;
  }

  const size_t arow0 = (size_t)by * 128;   // pixel-tile base
  const size_t brow0 = (size_t)bx * 128;   // col-block base

  f32x4 acc[4][4];
#pragma unroll
  for (int i = 0; i < 4; ++i)
#pragma unroll
    for (int j = 0; j < 4; ++j) { f32x4 z = {0.f, 0.f, 0.f, 0.f}; acc[i][j] = z; }

  const int q0 = tid, q1 = tid + 256;
  const int r0 = q0 >> 2, kk0 = q0 & 3;
  const int r1 = q1 >> 2, kk1 = q1 & 3;
  const uint16_t* a0 = A + (arow0 + r0) * KD + kk0 * 8;
  const uint16_t* a1 = A + (arow0 + r1) * KD + kk1 * 8;
  const uint16_t* b0 = Bw + (brow0 + r0) * KD + kk0 * 8;
  const uint16_t* b1 = Bw + (brow0 + r1) * KD + kk1 * 8;

  // One pipeline phase: stage tile @kn into (nA,nB), compute from (cA,cB).
  auto phase = [&](const uint16_t* cA, const uint16_t* cB,
                   uint16_t* nA, uint16_t* nB, int kn) {
    gld16(nA + q0 * 8, a0 + kn);
    gld16(nA + q1 * 8, a1 + kn);
    gld16(nB + q0 * 8, b0 + kn);
    gld16(nB + q1 * 8, b1 + kn);
    bf16x8 af[4], bfr[4];
#pragma unroll
    for (int mt = 0; mt < 4; ++mt)
      af[mt] = *(const bf16x8*)(const void*)
               (cA + (wm * 64 + mt * 16 + fm) * 32 + fq * 8);
#pragma unroll
    for (int nt = 0; nt < 4; ++nt)
      bfr[nt] = *(const bf16x8*)(const void*)
                (cB + (wn * 64 + nt * 16 + fm) * 32 + fq * 8);
#pragma unroll
    for (int mt = 0; mt < 4; ++mt)
#pragma unroll
      for (int nt = 0; nt < 4; ++nt)
        acc[mt][nt] = __builtin_amdgcn_mfma_f32_16x16x32_bf16(
            af[mt], bfr[nt], acc[mt][nt], 0, 0, 0);
    __syncthreads();   // drains vmcnt(0): staged tile ready; cur consumed
  };

  // Prologue: stage tile 0 into buf0; barrier drains vmcnt.
  gld16(A0 + q0 * 8, a0);
  gld16(A0 + q1 * 8, a1);
  gld16(B0 + q0 * 8, b0);
  gld16(B0 + q1 * 8, b1);
  __syncthreads();

  constexpr int NT = KD / 32;           // 8 (GEMM1) or 32 (GEMM2), even
#pragma unroll 1
  for (int t = 0; t < NT; t += 2) {
    phase(A0, B0, A1, B1, ((t + 1) & (NT - 1)) * 32);   // last even phase
    phase(A1, B1, A0, B0, ((t + 2) & (NT - 1)) * 32);   // wraps: redundant,
  }                                                      // harmless restage

  if (EPI == 0) {
    // fast GELU -> h, row-major (rows x 1024) bf16.
    // D layout: col=lane&15, row=fq*4+r (m89/m91 verified).
#pragma unroll
    for (int mt = 0; mt < 4; ++mt) {
      const size_t rb = arow0 + wm * 64 + mt * 16 + fq * 4;
#pragma unroll
      for (int nt = 0; nt < 4; ++nt) {
        const size_t n2 = brow0 + wn * 64 + nt * 16 + fm;
#pragma unroll
        for (int r = 0; r < 4; ++r)
          Cb16[(rb + r) * 1024 + n2] = f2bf(fast_gelu(acc[mt][nt][r]));
      }
    }
  } else {
    // Transpose through LDS -> pixel-contiguous NCHW fp32 stores + residual.
    __syncthreads();
#pragma unroll
    for (int mt = 0; mt < 4; ++mt) {
      int mbase = wm * 64 + mt * 16 + fq * 4;     // pixel within tile
#pragma unroll
      for (int nt = 0; nt < 4; ++nt) {
        int nn = wn * 64 + nt * 16 + fm;          // channel within tile
#pragma unroll
        for (int r = 0; r < 4; ++r)
          lds[nn * 130 + mbase + r] = f2bf(acc[mt][nt][r]);
      }
    }
    __syncthreads();
    const int pl0 = tid & 31;
    const int cw = tid >> 5;
#pragma unroll
    for (int it = 0; it < 16; ++it) {
      int ch = cw + it * 8;                        // channel within tile
      int cgl = (int)brow0 + ch;                   // global channel
#pragma unroll
      for (int e = 0; e < 4; ++e) {
        int pl = pl0 + e * 32;                     // pixel within tile
        uint32_t pg = (uint32_t)chunk_pix0 + by * 128u + (uint32_t)pl;
        uint32_t bimg = pg / 3136u;
        uint32_t rem = pg - bimg * 3136u;
        size_t addr = ((size_t)bimg * 256 + cgl) * 3136 + rem;
        Cf32[addr] = bf2f(lds[ch * 130 + pl]) + Xres[addr];
      }
    }
  }
}

// ---------------------------------------------------------------------------
// Launch: cvt weights -> neocell -> y1 (ws). Then (single pass if ws allows):
//   GEMM1 (K=256)  y1 @ fc1^T -> gelu -> h (bf16, ws)
//   GEMM2 (K=1024) h @ fc2^T + x -> out (fp32 NCHW)
// Chunking reverted (r4: L3-chunking was time-neutral — GEMMs are
// latency-bound, and halved grids cost co-residency + 2 extra launches).
// ---------------------------------------------------------------------------
extern "C" void kernel_launch(void* const* d_in, const int* in_sizes, int n_in,
                              void* d_out, int out_size, void* d_ws,
                              size_t ws_size, hipStream_t stream)
{
  const float* x   = (const float*)d_in[0];
  const float* wa1 = (const float*)d_in[1];
  const float* wb1 = (const float*)d_in[2];
  const float* wa2 = (const float*)d_in[3];
  const float* wb2 = (const float*)d_in[4];
  const float* bnw = (const float*)d_in[5];
  const float* bnb = (const float*)d_in[6];
  const float* bnm = (const float*)d_in[7];
  const float* bnv = (const float*)d_in[8];
  const float* fc1 = (const float*)d_in[9];
  const float* fc2 = (const float*)d_in[10];
  float* out = (float*)d_out;

  uint16_t* fc1b = (uint16_t*)d_ws;                 // 512 KB
  uint16_t* fc2b = fc1b + 262144;                   // 512 KB
  uint16_t* y1 = fc2b + 262144;                     // 51.4 MB
  const size_t y1_elems = (size_t)100352 * 256;
  uint16_t* h = y1 + y1_elems;

  const long tiles_total = 784;                     // 100352 / 128
  const size_t fixed_bytes = (size_t)262144 * 4 + y1_elems * 2;
  long tiles_chunk = 1;
  if (ws_size > fixed_bytes + 262144) {
    tiles_chunk = (long)((ws_size - fixed_bytes) / (128ul * 1024ul * 2ul));
    if (tiles_chunk > tiles_total) tiles_chunk = tiles_total;
    if (tiles_chunk < 1) tiles_chunk = 1;
  }

  cvt_weights_kernel<<<512, 256, 0, stream>>>(fc1, fc2, fc1b, fc2b);
  neocell_bn_kernel<<<dim3(14, 32, 4), 128, 0, stream>>>(
      x, wa1, wb1, wa2, wb2, bnw, bnb, bnm, bnv, y1);

  for (long t0 = 0; t0 < tiles_total; t0 += tiles_chunk) {
    long T = tiles_total - t0;
    if (T > tiles_chunk) T = tiles_chunk;
    gemm_bt_kernel<256, 0><<<dim3(8, (uint32_t)T), 256, 0, stream>>>(
        y1 + (size_t)t0 * 128 * 256, fc1b, h, nullptr, nullptr, 0);
    gemm_bt_kernel<1024, 1><<<dim3(2, (uint32_t)T), 256, 0, stream>>>(
        h, fc2b, nullptr, out, x, (int)(t0 * 128));
  }
}